// Round 14
// baseline (476.103 us; speedup 1.0000x reference)
//
#include <hip/hip_runtime.h>
#include <math.h>

#define THREADS 256
#define HIST_ILP 8
#define EPB_SHIFT 11   // edges per hist block = THREADS*HIST_ILP = 2048

static inline int cdiv(long long a, long long b) { return (int)((a + b - 1) / b); }

typedef __attribute__((ext_vector_type(8))) short bf16x8;
typedef __attribute__((ext_vector_type(4))) float f32x4;

__device__ inline unsigned f2bf_rne_u(float f) {
    unsigned u = __builtin_bit_cast(unsigned, f);
    return (u + 0x7FFFu + ((u >> 16) & 1u)) >> 16;
}
__device__ inline float bfu2f(unsigned h) {
    unsigned u = h << 16;
    return __builtin_bit_cast(float, u);
}

// ================= device bodies =================

__device__ __forceinline__ void bfrag_unit(const float* __restrict__ W, short* __restrict__ frag,
                                           int NCT, int ctks, int lane) {
    int Nn = NCT * 16;
    int ct = ctks % NCT;
    int ks = ctks / NCT;
    int colc = ct * 16 + (lane & 15);
    int kbase = ks * 32 + (lane >> 4) * 8;
    short* base = frag + (size_t)ctks * 1024 + lane * 8;
    #pragma unroll
    for (int j = 0; j < 8; ++j) {
        float v = W[(size_t)(kbase + j) * Nn + colc];
        unsigned h = f2bf_rne_u(v);
        base[j] = (short)h;
        base[512 + j] = (short)f2bf_rne_u(v - bfu2f(h));
    }
}

// shared-deg histogram + rank, 8 edges/thread
__device__ __forceinline__ void hist_body8(const int* __restrict__ dst, int* __restrict__ deg,
                                           int* __restrict__ rank, int E, int hb) {
    int base = (hb << EPB_SHIFT) + (int)threadIdx.x * HIST_ILP;
    if (base + HIST_ILP - 1 < E) {
        int4 d0 = *(const int4*)(dst + base);
        int4 d1 = *(const int4*)(dst + base + 4);
        int4 r0, r1;
        r0.x = atomicAdd(&deg[d0.x], 1);
        r0.y = atomicAdd(&deg[d0.y], 1);
        r0.z = atomicAdd(&deg[d0.z], 1);
        r0.w = atomicAdd(&deg[d0.w], 1);
        r1.x = atomicAdd(&deg[d1.x], 1);
        r1.y = atomicAdd(&deg[d1.y], 1);
        r1.z = atomicAdd(&deg[d1.z], 1);
        r1.w = atomicAdd(&deg[d1.w], 1);
        *(int4*)(rank + base) = r0;
        *(int4*)(rank + base + 4) = r1;
    } else {
        for (int e = base; e < E; ++e) rank[e] = atomicAdd(&deg[dst[e]], 1);
    }
}

// split-bf16 MFMA GEMM body (round-8 form: no prefetch, no setprio).
// Writes H = bf16(A @ W), unscaled.
template<int NCT, int KS>
__device__ __forceinline__ void gemm_body(const float* __restrict__ A, const short* __restrict__ Bfrag,
                                          unsigned short* __restrict__ H, int M, int blk) {
    constexpr int K = KS * 32;
    constexpr int Nn = NCT * 16;
    const int lane = threadIdx.x & 63;
    const int wave = threadIdx.x >> 6;
    const int rowBase = blk * 128 + wave * 32;
    const int arow0 = rowBase + (lane & 15);
    const int kgrp = (lane >> 4) * 8;

    f32x4 acc[2][NCT] = {};

    for (int ks = 0; ks < KS; ++ks) {
        const int kbase = ks * 32 + kgrp;
        bf16x8 ahi[2], alo[2];
        #pragma unroll
        for (int t = 0; t < 2; ++t) {
            int r = arow0 + t * 16;
            if (r >= M) r = M - 1;   // clamp; rows >= M masked on store
            const float* ap = A + (size_t)r * K + kbase;
            float4 v0 = *(const float4*)ap;
            float4 v1 = *(const float4*)(ap + 4);
            float av[8] = {v0.x, v0.y, v0.z, v0.w, v1.x, v1.y, v1.z, v1.w};
            #pragma unroll
            for (int j = 0; j < 8; ++j) {
                unsigned h = f2bf_rne_u(av[j]);
                ahi[t][j] = (short)h;
                alo[t][j] = (short)f2bf_rne_u(av[j] - bfu2f(h));
            }
        }
        #pragma unroll
        for (int ct = 0; ct < NCT; ++ct) {
            const short* bp = Bfrag + (size_t)(ks * NCT + ct) * 1024 + lane * 8;
            bf16x8 bhi = *(const bf16x8*)bp;
            bf16x8 blo = *(const bf16x8*)(bp + 512);
            #pragma unroll
            for (int t = 0; t < 2; ++t) {
                acc[t][ct] = __builtin_amdgcn_mfma_f32_16x16x32_bf16(ahi[t], bhi, acc[t][ct], 0, 0, 0);
                acc[t][ct] = __builtin_amdgcn_mfma_f32_16x16x32_bf16(ahi[t], blo, acc[t][ct], 0, 0, 0);
                acc[t][ct] = __builtin_amdgcn_mfma_f32_16x16x32_bf16(alo[t], bhi, acc[t][ct], 0, 0, 0);
            }
        }
    }

    // C/D layout: col = lane&15, row(within 16-tile) = (lane>>4)*4 + reg
    const int drow0 = rowBase + (lane >> 4) * 4;
    #pragma unroll
    for (int t = 0; t < 2; ++t) {
        #pragma unroll
        for (int r = 0; r < 4; ++r) {
            int row = drow0 + t * 16 + r;
            if (row < M) {
                unsigned short* hp = H + (size_t)row * Nn + (lane & 15);
                #pragma unroll
                for (int ct = 0; ct < NCT; ++ct)
                    hp[ct * 16] = (unsigned short)f2bf_rne_u(acc[t][ct][r]);
            }
        }
    }
}

// ================= kernels =================

// K0: [zero deg | bfrag]
__global__ __launch_bounds__(THREADS)
void zero_bfrag_kernel(int* __restrict__ deg, int N,
                       const float* __restrict__ W1, short* __restrict__ bf1,
                       const float* __restrict__ W2, short* __restrict__ bf2, int nbZero) {
    int b = (int)blockIdx.x;
    if (b < nbZero) {
        int base = (b * THREADS + (int)threadIdx.x) * 4;
        if (base + 3 < N) {
            *(int4*)(deg + base) = make_int4(0, 0, 0, 0);
        } else {
            for (int i = base; i < N; ++i) deg[i] = 0;
        }
    } else {
        int u = (b - nbZero) * 4 + ((int)threadIdx.x >> 6);
        int lane = threadIdx.x & 63;
        if (u < 64) bfrag_unit(W1, bf1, 8, u, lane);
        else if (u < 80) bfrag_unit(W2, bf2, 4, u - 64, lane);
    }
}

// K1: [hist || FULL gemm1] Bresenham-interleaved (round-8 proven)
__global__ __launch_bounds__(THREADS)
void hist_gemm1_kernel(const int* __restrict__ dst, int* __restrict__ deg,
                       int* __restrict__ rank, int E,
                       const float* __restrict__ A, const short* __restrict__ Bfrag,
                       unsigned short* __restrict__ H, int M,
                       int nbHist, int nbGemm) {
    int b = (int)blockIdx.x;
    int total = nbHist + nbGemm;
    long long t = (long long)b * nbGemm;
    int gBefore = (int)(t / total);
    bool isG = (((long long)(b + 1) * nbGemm) / total) > gBefore;
    if (isG) gemm_body<8, 8>(A, Bfrag, H, M, gBefore);
    else     hist_body8(dst, deg, rank, E, b - gBefore);
}

// CSR fill, atomic-free, 4 edges/thread
__global__ __launch_bounds__(THREADS)
void fill_col_rank_kernel(const int* __restrict__ src, const int* __restrict__ dst,
                          const int* __restrict__ rank, const int* __restrict__ rowptr,
                          int* __restrict__ col, int E) {
    int base = ((int)blockIdx.x * THREADS + (int)threadIdx.x) * 4;
    if (base + 3 < E) {
        int4 d = *(const int4*)(dst + base);
        int4 r = *(const int4*)(rank + base);
        int4 s = *(const int4*)(src + base);
        col[rowptr[d.x] + r.x] = s.x;
        col[rowptr[d.y] + r.y] = s.y;
        col[rowptr[d.z] + r.z] = s.z;
        col[rowptr[d.w] + r.w] = s.w;
    } else {
        for (int e = base; e < E; ++e)
            col[rowptr[dst[e]] + rank[e]] = src[e];
    }
}

// standalone GEMM (layer 2)
template<int NCT, int KS>
__global__ __launch_bounds__(THREADS)
void mfma_gemm_bf16out_kernel(const float* __restrict__ A, const short* __restrict__ Bfrag,
                              unsigned short* __restrict__ H, int M) {
    gemm_body<NCT, KS>(A, Bfrag, H, M, (int)blockIdx.x);
}

// ================= exclusive scan, fused dis =================

#define SCAN_BLOCK 256
#define SCAN_ITEMS 4   // 1024 elements per block

__global__ __launch_bounds__(SCAN_BLOCK)
void scan_block_kernel(const int* __restrict__ in, int* __restrict__ out,
                       int* __restrict__ blockSums, float* __restrict__ dis, int n) {
    __shared__ int sdata[SCAN_BLOCK];
    int base = blockIdx.x * (SCAN_BLOCK * SCAN_ITEMS);
    int tid = threadIdx.x;
    int v[SCAN_ITEMS];
    int sum = 0;
    #pragma unroll
    for (int k = 0; k < SCAN_ITEMS; ++k) {
        int idx = base + tid * SCAN_ITEMS + k;
        v[k] = (idx < n) ? in[idx] : 0;
        if (idx < n) dis[idx] = rsqrtf((float)v[k] + 1.0f);
        sum += v[k];
    }
    sdata[tid] = sum;
    __syncthreads();
    for (int off = 1; off < SCAN_BLOCK; off <<= 1) {
        int t = (tid >= off) ? sdata[tid - off] : 0;
        __syncthreads();
        sdata[tid] += t;
        __syncthreads();
    }
    if (tid == SCAN_BLOCK - 1) blockSums[blockIdx.x] = sdata[SCAN_BLOCK - 1];
    int run = (tid == 0) ? 0 : sdata[tid - 1];
    #pragma unroll
    for (int k = 0; k < SCAN_ITEMS; ++k) {
        int idx = base + tid * SCAN_ITEMS + k;
        if (idx < n) out[idx] = run;
        run += v[k];
    }
}

__global__ __launch_bounds__(SCAN_BLOCK)
void scan_sums_kernel(int* __restrict__ blockSums, int nB) {
    __shared__ int sdata[SCAN_BLOCK];
    int tid = threadIdx.x;
    sdata[tid] = (tid < nB) ? blockSums[tid] : 0;
    __syncthreads();
    for (int off = 1; off < SCAN_BLOCK; off <<= 1) {
        int t = (tid >= off) ? sdata[tid - off] : 0;
        __syncthreads();
        sdata[tid] += t;
        __syncthreads();
    }
    int excl = (tid == 0) ? 0 : sdata[tid - 1];
    if (tid < nB) blockSums[tid] = excl;
}

__global__ __launch_bounds__(SCAN_BLOCK)
void scan_add_kernel(int* __restrict__ out, const int* __restrict__ blockSums,
                     int n, int E) {
    int base = blockIdx.x * (SCAN_BLOCK * SCAN_ITEMS);
    int add = blockSums[blockIdx.x];
    #pragma unroll
    for (int k = 0; k < SCAN_ITEMS; ++k) {
        int idx = base + threadIdx.x * SCAN_ITEMS + k;
        if (idx < n) out[idx] += add;
    }
    if (blockIdx.x == 0 && threadIdx.x == 0) out[n] = E;
}

// ================= XCD column-partitioned gather (F=128) =================
// Class = blockIdx & 7 (round-robins XCDs); each class covers 16 of 128 cols
// (32B of the 256B row) -> per-XCD g working set 3.2MB, L2-resident.
// Wave = one (node, class): 8 edge-slots x 8 lanes, VEC2 per lane.
// out_i = relu(di * (di*h_i + sum_s dis[s]*h_s) + b).

__global__ __launch_bounds__(THREADS)
void gather_split128_kernel(const unsigned short* __restrict__ g, const int* __restrict__ col,
                            const int* __restrict__ rowptr, const float* __restrict__ dis,
                            const float* __restrict__ bias, float* __restrict__ out, int N) {
    const int b = (int)blockIdx.x;
    const int cls = b & 7;
    const int wave = (int)threadIdx.x >> 6;
    const int node = (b >> 3) * 4 + wave;
    if (node >= N) return;
    const int lane = threadIdx.x & 63;
    const int slot = lane >> 3;       // 0..7 edge slots
    const int q = lane & 7;           // lane within slot
    const int colbase = cls * 16 + q * 2;   // bf16 element offset in row

    const float di = dis[node];
    float a0 = 0.0f, a1 = 0.0f;

    auto loadrow = [&](int s) -> unsigned {
        return *(const unsigned*)(g + (size_t)s * 128 + colbase);
    };
    auto addconv = [&](unsigned u, float w) {
        a0 += w * bfu2f(u & 0xFFFFu);
        a1 += w * __builtin_bit_cast(float, u & 0xFFFF0000u);
    };

    if (slot == 0) addconv(loadrow(node), di);   // self row once

    const int start = rowptr[node], end = rowptr[node + 1];
    int j = start + slot;

    // depth-2 per slot (16 edges in flight per wave)
    if (j + 8 < end) {
        int s0 = col[j];
        int s1 = col[j + 8];
        float w0 = dis[s0], w1 = dis[s1];
        unsigned u0 = loadrow(s0), u1 = loadrow(s1);
        j += 16;
        while (j < end) {
            int s2 = col[j];
            float w2 = dis[s2];
            unsigned u2 = loadrow(s2);
            addconv(u0, w0);
            u0 = u1; w0 = w1;
            u1 = u2; w1 = w2;
            j += 8;
        }
        addconv(u0, w0);
        addconv(u1, w1);
    } else if (j < end) {
        int s0 = col[j];
        addconv(loadrow(s0), dis[s0]);
        j += 8;
        if (j < end) {
            int s1 = col[j];
            addconv(loadrow(s1), dis[s1]);
        }
    }

    // fold the 8 slots (lanes q, q+8, ..., q+56)
    a0 += __shfl_xor(a0, 8);  a1 += __shfl_xor(a1, 8);
    a0 += __shfl_xor(a0, 16); a1 += __shfl_xor(a1, 16);
    a0 += __shfl_xor(a0, 32); a1 += __shfl_xor(a1, 32);

    if (slot == 0) {
        float v0 = fmaxf(di * a0 + bias[colbase + 0], 0.0f);
        float v1 = fmaxf(di * a1 + bias[colbase + 1], 0.0f);
        *(float2*)(out + (size_t)node * 128 + colbase) = make_float2(v0, v1);
    }
}

// ================= scalarized gather, depth-8 pipeline (F=64 layer 2) =================

template<int F, int VEC>
__global__ __launch_bounds__(THREADS)
void gather_bf16_kernel(const unsigned short* __restrict__ g, const int* __restrict__ col,
                        const int* __restrict__ rowptr, const float* __restrict__ dis,
                        const float* __restrict__ bias, float* __restrict__ out, int N) {
    int wid = (int)((blockIdx.x * (long long)blockDim.x + threadIdx.x) >> 6);
    wid = __builtin_amdgcn_readfirstlane(wid);
    const int lane = threadIdx.x & 63;
    if (wid >= N) return;
    const float di = dis[wid];
    const int loff = lane * VEC;

    float acc0 = 0.0f, acc1 = 0.0f;

    auto loadrow = [&](int s) -> unsigned {
        const unsigned short* p = g + (size_t)s * F + loff;
        if (VEC == 2) return *(const unsigned*)p;
        else return (unsigned)*p;
    };
    auto addconv = [&](unsigned u, float w) {
        if (VEC == 2) {
            acc0 += w * bfu2f(u & 0xFFFFu);
            acc1 += w * __builtin_bit_cast(float, u & 0xFFFF0000u);
        } else {
            acc0 += w * bfu2f(u);
        }
    };

    addconv(loadrow(wid), di);   // self-loop row

    int start = __builtin_amdgcn_readfirstlane(rowptr[wid]);
    int end   = __builtin_amdgcn_readfirstlane(rowptr[wid + 1]);
    const int* c = col + start;
    int rem = end - start;

    if (rem >= 8) {
        int s0 = __builtin_amdgcn_readfirstlane(c[0]);
        int s1 = __builtin_amdgcn_readfirstlane(c[1]);
        int s2 = __builtin_amdgcn_readfirstlane(c[2]);
        int s3 = __builtin_amdgcn_readfirstlane(c[3]);
        int s4 = __builtin_amdgcn_readfirstlane(c[4]);
        int s5 = __builtin_amdgcn_readfirstlane(c[5]);
        int s6 = __builtin_amdgcn_readfirstlane(c[6]);
        int s7 = __builtin_amdgcn_readfirstlane(c[7]);
        float w0 = dis[s0], w1 = dis[s1], w2 = dis[s2], w3 = dis[s3];
        float w4 = dis[s4], w5 = dis[s5], w6 = dis[s6], w7 = dis[s7];
        unsigned u0 = loadrow(s0), u1 = loadrow(s1), u2 = loadrow(s2), u3 = loadrow(s3);
        unsigned u4 = loadrow(s4), u5 = loadrow(s5), u6 = loadrow(s6), u7 = loadrow(s7);
        c += 8; rem -= 8;
        while (rem >= 8) {
            int t0 = __builtin_amdgcn_readfirstlane(c[0]);
            int t1 = __builtin_amdgcn_readfirstlane(c[1]);
            int t2 = __builtin_amdgcn_readfirstlane(c[2]);
            int t3 = __builtin_amdgcn_readfirstlane(c[3]);
            int t4 = __builtin_amdgcn_readfirstlane(c[4]);
            int t5 = __builtin_amdgcn_readfirstlane(c[5]);
            int t6 = __builtin_amdgcn_readfirstlane(c[6]);
            int t7 = __builtin_amdgcn_readfirstlane(c[7]);
            float x0 = dis[t0], x1 = dis[t1], x2 = dis[t2], x3 = dis[t3];
            float x4 = dis[t4], x5 = dis[t5], x6 = dis[t6], x7 = dis[t7];
            unsigned v0 = loadrow(t0), v1 = loadrow(t1), v2 = loadrow(t2), v3 = loadrow(t3);
            unsigned v4 = loadrow(t4), v5 = loadrow(t5), v6 = loadrow(t6), v7 = loadrow(t7);
            addconv(u0, w0); addconv(u1, w1); addconv(u2, w2); addconv(u3, w3);
            addconv(u4, w4); addconv(u5, w5); addconv(u6, w6); addconv(u7, w7);
            u0 = v0; u1 = v1; u2 = v2; u3 = v3;
            u4 = v4; u5 = v5; u6 = v6; u7 = v7;
            w0 = x0; w1 = x1; w2 = x2; w3 = x3;
            w4 = x4; w5 = x5; w6 = x6; w7 = x7;
            c += 8; rem -= 8;
        }
        addconv(u0, w0); addconv(u1, w1); addconv(u2, w2); addconv(u3, w3);
        addconv(u4, w4); addconv(u5, w5); addconv(u6, w6); addconv(u7, w7);
    }
    if (rem >= 4) {
        int s0 = __builtin_amdgcn_readfirstlane(c[0]);
        int s1 = __builtin_amdgcn_readfirstlane(c[1]);
        int s2 = __builtin_amdgcn_readfirstlane(c[2]);
        int s3 = __builtin_amdgcn_readfirstlane(c[3]);
        float w0 = dis[s0], w1 = dis[s1], w2 = dis[s2], w3 = dis[s3];
        unsigned u0 = loadrow(s0), u1 = loadrow(s1), u2 = loadrow(s2), u3 = loadrow(s3);
        addconv(u0, w0); addconv(u1, w1); addconv(u2, w2); addconv(u3, w3);
        c += 4; rem -= 4;
    }
    while (rem > 0) {
        int s = __builtin_amdgcn_readfirstlane(c[0]);
        addconv(loadrow(s), dis[s]);
        ++c; --rem;
    }

    float* orow = out + (size_t)wid * F + loff;
    float v0 = di * acc0 + bias[loff];
    if (VEC == 2) {
        float v1 = di * acc1 + bias[loff + 1];
        *(float2*)orow = make_float2(fmaxf(v0, 0.0f), fmaxf(v1, 0.0f));
    } else {
        *orow = fmaxf(v0, 0.0f);
    }
}

// ================= fallback fp32 GEMM + atomic path (round-0, verified) =================

#define BM 64
#define BN 64
#define BK 16

__global__ __launch_bounds__(THREADS)
void sgemm_kernel(const float* __restrict__ A, const float* __restrict__ B,
                  float* __restrict__ C, int M, int N, int K) {
    __shared__ float As[BK][BM + 1];
    __shared__ float Bs[BK][BN + 1];

    const int tid = threadIdx.x;
    const int tr = tid / 16;
    const int tc = tid % 16;
    const int rowBase = blockIdx.y * BM;
    const int colBase = blockIdx.x * BN;

    float acc[4][4] = {};

    for (int k0 = 0; k0 < K; k0 += BK) {
        #pragma unroll
        for (int i = tid; i < BM * BK; i += THREADS) {
            int r = i / BK, c = i % BK;
            int gr = rowBase + r;
            As[c][r] = (gr < M) ? A[(size_t)gr * K + k0 + c] : 0.0f;
        }
        #pragma unroll
        for (int i = tid; i < BK * BN; i += THREADS) {
            int r = i / BN, c = i % BN;
            Bs[r][c] = B[(size_t)(k0 + r) * N + colBase + c];
        }
        __syncthreads();

        #pragma unroll
        for (int k = 0; k < BK; ++k) {
            float a[4], b[4];
            #pragma unroll
            for (int m = 0; m < 4; ++m) a[m] = As[k][tr * 4 + m];
            #pragma unroll
            for (int n = 0; n < 4; ++n) b[n] = Bs[k][tc * 4 + n];
            #pragma unroll
            for (int m = 0; m < 4; ++m)
                #pragma unroll
                for (int n = 0; n < 4; ++n)
                    acc[m][n] += a[m] * b[n];
        }
        __syncthreads();
    }

    #pragma unroll
    for (int m = 0; m < 4; ++m) {
        int gr = rowBase + tr * 4 + m;
        if (gr >= M) continue;
        #pragma unroll
        for (int n = 0; n < 4; ++n) {
            C[(size_t)gr * N + colBase + tc * 4 + n] = acc[m][n];
        }
    }
}

__global__ __launch_bounds__(THREADS)
void init_agg_kernel(const float* __restrict__ h, const float* __restrict__ dis,
                     float* __restrict__ agg, int N, int F) {
    int i = blockIdx.x * blockDim.x + threadIdx.x;
    int total = N * (F / 4);
    if (i >= total) return;
    int node = i / (F / 4);
    float d = dis[node];
    float w = d * d;
    float4 v = ((const float4*)h)[i];
    v.x *= w; v.y *= w; v.z *= w; v.w *= w;
    ((float4*)agg)[i] = v;
}

__global__ __launch_bounds__(THREADS)
void edge_scatter_kernel(const float* __restrict__ h, const int* __restrict__ src,
                         const int* __restrict__ dst, const float* __restrict__ dis,
                         float* __restrict__ agg, int E, int F) {
    int lanesPerEdge = F / 4;
    int tid = blockIdx.x * blockDim.x + threadIdx.x;
    int e = tid / lanesPerEdge;
    int c = tid % lanesPerEdge;
    if (e >= E) return;
    int s = src[e];
    int d = dst[e];
    float w = dis[s] * dis[d];
    float4 hv = ((const float4*)(h + (size_t)s * F))[c];
    float* ap = agg + (size_t)d * F + (size_t)c * 4;
    atomicAdd(ap + 0, hv.x * w);
    atomicAdd(ap + 1, hv.y * w);
    atomicAdd(ap + 2, hv.z * w);
    atomicAdd(ap + 3, hv.w * w);
}

__global__ __launch_bounds__(THREADS)
void finalize_kernel(const float* __restrict__ agg, const float* __restrict__ b,
                     float* __restrict__ out, int N, int F) {
    int i = blockIdx.x * blockDim.x + threadIdx.x;
    int total = N * (F / 4);
    if (i >= total) return;
    int c4 = i % (F / 4);
    float4 bv = ((const float4*)b)[c4];
    float4 v = ((const float4*)agg)[i];
    v.x = fmaxf(v.x + bv.x, 0.0f);
    v.y = fmaxf(v.y + bv.y, 0.0f);
    v.z = fmaxf(v.z + bv.z, 0.0f);
    v.w = fmaxf(v.w + bv.w, 0.0f);
    ((float4*)out)[i] = v;
}

__global__ __launch_bounds__(THREADS)
void fdeg_kernel(const int* __restrict__ dst, float* __restrict__ deg, int E) {
    int i = blockIdx.x * blockDim.x + threadIdx.x;
    if (i < E) atomicAdd(&deg[dst[i]], 1.0f);
}

__global__ __launch_bounds__(THREADS)
void fdis_kernel(float* __restrict__ deg, int N) {
    int i = blockIdx.x * blockDim.x + threadIdx.x;
    if (i < N) deg[i] = rsqrtf(deg[i] + 1.0f);
}

// ================= launch =================

extern "C" void kernel_launch(void* const* d_in, const int* in_sizes, int n_in,
                              void* d_out, int out_size, void* d_ws, size_t ws_size,
                              hipStream_t stream) {
    const float* x  = (const float*)d_in[0];
    const int*   ei = (const int*)d_in[1];
    const float* W1 = (const float*)d_in[2];
    const float* b1 = (const float*)d_in[3];
    const float* W2 = (const float*)d_in[4];
    const float* b2 = (const float*)d_in[5];

    const int E    = in_sizes[1] / 2;
    const int hid  = in_sizes[3];            // 128
    const int outc = in_sizes[5];            // 64
    const int inc  = in_sizes[2] / hid;      // 256
    const int N    = in_sizes[0] / inc;      // 100000

    const int* src = ei;
    const int* dst = ei + E;
    float* out = (float*)d_out;
    char* ws = (char*)d_ws;

    auto al = [](size_t v) { return (v + 255) & ~(size_t)255; };
    size_t o_dis  = 0;
    size_t o_deg  = al(o_dis + (size_t)N * 4);
    size_t o_rp   = al(o_deg + (size_t)N * 4);
    size_t o_bs   = al(o_rp + ((size_t)N + 1) * 4);
    size_t o_col  = al(o_bs + 4096);
    size_t o_rank = al(o_col + (size_t)E * 4);
    size_t o_bf1  = al(o_rank + (size_t)E * 4);
    size_t o_bf2  = al(o_bf1 + 131072);                // 8*8*1024 shorts
    size_t o_G    = al(o_bf2 + 32768);                 // 4*4*1024 shorts
    size_t o_B    = al(o_G + (size_t)N * hid * 2);     // h rows (bf16)
    size_t need   = o_B + (size_t)N * hid * 4;         // out1 (fp32)

    if (ws_size >= need && N <= SCAN_BLOCK * SCAN_BLOCK * SCAN_ITEMS &&
        hid == 128 && outc == 64 && inc == 256) {
        // ---------- CSR gather + MFMA path (round-8 structure) ----------
        float* dis    = (float*)(ws + o_dis);
        int*   deg    = (int*)(ws + o_deg);
        int*   rowptr = (int*)(ws + o_rp);
        int*   bsums  = (int*)(ws + o_bs);
        int*   col    = (int*)(ws + o_col);
        int*   rank   = (int*)(ws + o_rank);
        short* bf1    = (short*)(ws + o_bf1);
        short* bf2    = (short*)(ws + o_bf2);
        unsigned short* gbuf = (unsigned short*)(ws + o_G);  // h1 bf16 (N*128), later h2 (N*64)
        float* out1   = (float*)(ws + o_B);     // fp32 layer-1 output

        const int nbZero  = cdiv(N, 4 * THREADS);
        const int nbHist  = cdiv(E, THREADS * HIST_ILP);
        const int nbGemm1 = cdiv(N, 128);
        const int nbFill  = cdiv(E, 4 * THREADS);

        // K0: zero deg || weight fragments
        zero_bfrag_kernel<<<nbZero + 20, THREADS, 0, stream>>>(deg, N, W1, bf1, W2, bf2, nbZero);

        // K1: hist (ILP-8) || FULL gemm1, Bresenham-interleaved
        hist_gemm1_kernel<<<nbHist + nbGemm1, THREADS, 0, stream>>>(
            dst, deg, rank, E, x, bf1, gbuf, N, nbHist, nbGemm1);

        // rowptr = exclusive_scan(deg); dis fused
        int nB = cdiv(N, SCAN_BLOCK * SCAN_ITEMS);
        scan_block_kernel<<<nB, SCAN_BLOCK, 0, stream>>>(deg, rowptr, bsums, dis, N);
        scan_sums_kernel<<<1, SCAN_BLOCK, 0, stream>>>(bsums, nB);
        scan_add_kernel<<<nB, SCAN_BLOCK, 0, stream>>>(rowptr, bsums, N, E);

        // CSR fill (atomic-free)
        fill_col_rank_kernel<<<nbFill, THREADS, 0, stream>>>(src, dst, rank, rowptr, col, E);

        // ---- layer 1 gather: XCD column-partitioned ----
        gather_split128_kernel<<<8 * cdiv(N, 4), THREADS, 0, stream>>>(
            gbuf, col, rowptr, dis, b1, out1, N);

        // ---- layer 2 ----
        mfma_gemm_bf16out_kernel<4, 4><<<cdiv(N, 128), THREADS, 0, stream>>>(out1, bf2, gbuf, N);
        gather_bf16_kernel<64, 1><<<cdiv((long long)N * 64, THREADS), THREADS, 0, stream>>>(
            gbuf, col, rowptr, dis, b2, out, N);
        return;
    }

    // ---------- fallback: round-0 atomic path ----------
    float* dis = (float*)ws;
    size_t off1 = ((size_t)N * 4 + 255) & ~(size_t)255;
    float* h1 = (float*)(ws + off1);
    size_t off2 = off1 + ((((size_t)N * hid * 4) + 255) & ~(size_t)255);
    float* agg1 = (float*)(ws + off2);
    float* h2   = agg1;
    float* agg2 = agg1 + (size_t)N * outc;

    hipMemsetAsync(dis, 0, (size_t)N * 4, stream);
    fdeg_kernel<<<cdiv(E, THREADS), THREADS, 0, stream>>>(dst, dis, E);
    fdis_kernel<<<cdiv(N, THREADS), THREADS, 0, stream>>>(dis, N);

    {
        dim3 grid(hid / BN, cdiv(N, BM));
        sgemm_kernel<<<grid, THREADS, 0, stream>>>(x, W1, h1, N, hid, inc);
    }
    init_agg_kernel<<<cdiv((long long)N * hid / 4, THREADS), THREADS, 0, stream>>>(h1, dis, agg1, N, hid);
    edge_scatter_kernel<<<cdiv((long long)E * (hid / 4), THREADS), THREADS, 0, stream>>>(
        h1, src, dst, dis, agg1, E, hid);
    finalize_kernel<<<cdiv((long long)N * hid / 4, THREADS), THREADS, 0, stream>>>(agg1, b1, h1, N, hid);

    {
        dim3 grid(outc / BN, cdiv(N, BM));
        sgemm_kernel<<<grid, THREADS, 0, stream>>>(h1, W2, h2, N, outc, hid);
    }
    init_agg_kernel<<<cdiv((long long)N * outc / 4, THREADS), THREADS, 0, stream>>>(h2, dis, agg2, N, outc);
    edge_scatter_kernel<<<cdiv((long long)E * (outc / 4), THREADS), THREADS, 0, stream>>>(
        h2, src, dst, dis, agg2, E, outc);
    finalize_kernel<<<cdiv((long long)N * outc / 4, THREADS), THREADS, 0, stream>>>(agg2, b2, out, N, outc);
}

// Round 15
// 242.942 us; speedup vs baseline: 1.9597x; 1.9597x over previous
//
#include <hip/hip_runtime.h>
#include <math.h>

#define THREADS 256
#define HIST_ILP 8
#define EPB_SHIFT 11   // edges per hist block = THREADS*HIST_ILP = 2048

static inline int cdiv(long long a, long long b) { return (int)((a + b - 1) / b); }

typedef __attribute__((ext_vector_type(8))) short bf16x8;
typedef __attribute__((ext_vector_type(4))) float f32x4;

__device__ inline unsigned f2bf_rne_u(float f) {
    unsigned u = __builtin_bit_cast(unsigned, f);
    return (u + 0x7FFFu + ((u >> 16) & 1u)) >> 16;
}
__device__ inline float bfu2f(unsigned h) {
    unsigned u = h << 16;
    return __builtin_bit_cast(float, u);
}

// ================= device bodies =================

__device__ __forceinline__ void bfrag_unit(const float* __restrict__ W, short* __restrict__ frag,
                                           int NCT, int ctks, int lane) {
    int Nn = NCT * 16;
    int ct = ctks % NCT;
    int ks = ctks / NCT;
    int colc = ct * 16 + (lane & 15);
    int kbase = ks * 32 + (lane >> 4) * 8;
    short* base = frag + (size_t)ctks * 1024 + lane * 8;
    #pragma unroll
    for (int j = 0; j < 8; ++j) {
        float v = W[(size_t)(kbase + j) * Nn + colc];
        unsigned h = f2bf_rne_u(v);
        base[j] = (short)h;
        base[512 + j] = (short)f2bf_rne_u(v - bfu2f(h));
    }
}

// shared-deg histogram + rank, 8 edges/thread
__device__ __forceinline__ void hist_body8(const int* __restrict__ dst, int* __restrict__ deg,
                                           int* __restrict__ rank, int E, int hb) {
    int base = (hb << EPB_SHIFT) + (int)threadIdx.x * HIST_ILP;
    if (base + HIST_ILP - 1 < E) {
        int4 d0 = *(const int4*)(dst + base);
        int4 d1 = *(const int4*)(dst + base + 4);
        int4 r0, r1;
        r0.x = atomicAdd(&deg[d0.x], 1);
        r0.y = atomicAdd(&deg[d0.y], 1);
        r0.z = atomicAdd(&deg[d0.z], 1);
        r0.w = atomicAdd(&deg[d0.w], 1);
        r1.x = atomicAdd(&deg[d1.x], 1);
        r1.y = atomicAdd(&deg[d1.y], 1);
        r1.z = atomicAdd(&deg[d1.z], 1);
        r1.w = atomicAdd(&deg[d1.w], 1);
        *(int4*)(rank + base) = r0;
        *(int4*)(rank + base + 4) = r1;
    } else {
        for (int e = base; e < E; ++e) rank[e] = atomicAdd(&deg[dst[e]], 1);
    }
}

// split-bf16 MFMA GEMM body, f32 A input (round-8 form). Writes H = bf16(A @ W).
template<int NCT, int KS>
__device__ __forceinline__ void gemm_body(const float* __restrict__ A, const short* __restrict__ Bfrag,
                                          unsigned short* __restrict__ H, int M, int blk) {
    constexpr int K = KS * 32;
    constexpr int Nn = NCT * 16;
    const int lane = threadIdx.x & 63;
    const int wave = threadIdx.x >> 6;
    const int rowBase = blk * 128 + wave * 32;
    const int arow0 = rowBase + (lane & 15);
    const int kgrp = (lane >> 4) * 8;

    f32x4 acc[2][NCT] = {};

    for (int ks = 0; ks < KS; ++ks) {
        const int kbase = ks * 32 + kgrp;
        bf16x8 ahi[2], alo[2];
        #pragma unroll
        for (int t = 0; t < 2; ++t) {
            int r = arow0 + t * 16;
            if (r >= M) r = M - 1;   // clamp; rows >= M masked on store
            const float* ap = A + (size_t)r * K + kbase;
            float4 v0 = *(const float4*)ap;
            float4 v1 = *(const float4*)(ap + 4);
            float av[8] = {v0.x, v0.y, v0.z, v0.w, v1.x, v1.y, v1.z, v1.w};
            #pragma unroll
            for (int j = 0; j < 8; ++j) {
                unsigned h = f2bf_rne_u(av[j]);
                ahi[t][j] = (short)h;
                alo[t][j] = (short)f2bf_rne_u(av[j] - bfu2f(h));
            }
        }
        #pragma unroll
        for (int ct = 0; ct < NCT; ++ct) {
            const short* bp = Bfrag + (size_t)(ks * NCT + ct) * 1024 + lane * 8;
            bf16x8 bhi = *(const bf16x8*)bp;
            bf16x8 blo = *(const bf16x8*)(bp + 512);
            #pragma unroll
            for (int t = 0; t < 2; ++t) {
                acc[t][ct] = __builtin_amdgcn_mfma_f32_16x16x32_bf16(ahi[t], bhi, acc[t][ct], 0, 0, 0);
                acc[t][ct] = __builtin_amdgcn_mfma_f32_16x16x32_bf16(ahi[t], blo, acc[t][ct], 0, 0, 0);
                acc[t][ct] = __builtin_amdgcn_mfma_f32_16x16x32_bf16(alo[t], bhi, acc[t][ct], 0, 0, 0);
            }
        }
    }

    // C/D layout: col = lane&15, row(within 16-tile) = (lane>>4)*4 + reg
    const int drow0 = rowBase + (lane >> 4) * 4;
    #pragma unroll
    for (int t = 0; t < 2; ++t) {
        #pragma unroll
        for (int r = 0; r < 4; ++r) {
            int row = drow0 + t * 16 + r;
            if (row < M) {
                unsigned short* hp = H + (size_t)row * Nn + (lane & 15);
                #pragma unroll
                for (int ct = 0; ct < NCT; ++ct)
                    hp[ct * 16] = (unsigned short)f2bf_rne_u(acc[t][ct][r]);
            }
        }
    }
}

// bf16-A MFMA GEMM body (layer 2): A is bf16 rows; W split hi+lo (2 MFMAs/tile).
template<int NCT, int KS>
__device__ __forceinline__ void gemm_bf16A_body(const unsigned short* __restrict__ A,
                                                const short* __restrict__ Bfrag,
                                                unsigned short* __restrict__ H, int M, int blk) {
    constexpr int K = KS * 32;
    constexpr int Nn = NCT * 16;
    const int lane = threadIdx.x & 63;
    const int wave = threadIdx.x >> 6;
    const int rowBase = blk * 128 + wave * 32;
    const int arow0 = rowBase + (lane & 15);
    const int kgrp = (lane >> 4) * 8;

    f32x4 acc[2][NCT] = {};

    for (int ks = 0; ks < KS; ++ks) {
        const int kbase = ks * 32 + kgrp;
        bf16x8 a[2];
        #pragma unroll
        for (int t = 0; t < 2; ++t) {
            int r = arow0 + t * 16;
            if (r >= M) r = M - 1;
            a[t] = *(const bf16x8*)(A + (size_t)r * K + kbase);
        }
        #pragma unroll
        for (int ct = 0; ct < NCT; ++ct) {
            const short* bp = Bfrag + (size_t)(ks * NCT + ct) * 1024 + lane * 8;
            bf16x8 bhi = *(const bf16x8*)bp;
            bf16x8 blo = *(const bf16x8*)(bp + 512);
            #pragma unroll
            for (int t = 0; t < 2; ++t) {
                acc[t][ct] = __builtin_amdgcn_mfma_f32_16x16x32_bf16(a[t], bhi, acc[t][ct], 0, 0, 0);
                acc[t][ct] = __builtin_amdgcn_mfma_f32_16x16x32_bf16(a[t], blo, acc[t][ct], 0, 0, 0);
            }
        }
    }

    const int drow0 = rowBase + (lane >> 4) * 4;
    #pragma unroll
    for (int t = 0; t < 2; ++t) {
        #pragma unroll
        for (int r = 0; r < 4; ++r) {
            int row = drow0 + t * 16 + r;
            if (row < M) {
                unsigned short* hp = H + (size_t)row * Nn + (lane & 15);
                #pragma unroll
                for (int ct = 0; ct < NCT; ++ct)
                    hp[ct * 16] = (unsigned short)f2bf_rne_u(acc[t][ct][r]);
            }
        }
    }
}

// ================= kernels =================

// K0: [zero deg | bfrag]
__global__ __launch_bounds__(THREADS)
void zero_bfrag_kernel(int* __restrict__ deg, int N,
                       const float* __restrict__ W1, short* __restrict__ bf1,
                       const float* __restrict__ W2, short* __restrict__ bf2, int nbZero) {
    int b = (int)blockIdx.x;
    if (b < nbZero) {
        int base = (b * THREADS + (int)threadIdx.x) * 4;
        if (base + 3 < N) {
            *(int4*)(deg + base) = make_int4(0, 0, 0, 0);
        } else {
            for (int i = base; i < N; ++i) deg[i] = 0;
        }
    } else {
        int u = (b - nbZero) * 4 + ((int)threadIdx.x >> 6);
        int lane = threadIdx.x & 63;
        if (u < 64) bfrag_unit(W1, bf1, 8, u, lane);
        else if (u < 80) bfrag_unit(W2, bf2, 4, u - 64, lane);
    }
}

// K1: [hist || FULL gemm1] Bresenham-interleaved (round-8 proven)
__global__ __launch_bounds__(THREADS)
void hist_gemm1_kernel(const int* __restrict__ dst, int* __restrict__ deg,
                       int* __restrict__ rank, int E,
                       const float* __restrict__ A, const short* __restrict__ Bfrag,
                       unsigned short* __restrict__ H, int M,
                       int nbHist, int nbGemm) {
    int b = (int)blockIdx.x;
    int total = nbHist + nbGemm;
    long long t = (long long)b * nbGemm;
    int gBefore = (int)(t / total);
    bool isG = (((long long)(b + 1) * nbGemm) / total) > gBefore;
    if (isG) gemm_body<8, 8>(A, Bfrag, H, M, gBefore);
    else     hist_body8(dst, deg, rank, E, b - gBefore);
}

// CSR fill, atomic-free, 4 edges/thread
__global__ __launch_bounds__(THREADS)
void fill_col_rank_kernel(const int* __restrict__ src, const int* __restrict__ dst,
                          const int* __restrict__ rank, const int* __restrict__ rowptr,
                          int* __restrict__ col, int E) {
    int base = ((int)blockIdx.x * THREADS + (int)threadIdx.x) * 4;
    if (base + 3 < E) {
        int4 d = *(const int4*)(dst + base);
        int4 r = *(const int4*)(rank + base);
        int4 s = *(const int4*)(src + base);
        col[rowptr[d.x] + r.x] = s.x;
        col[rowptr[d.y] + r.y] = s.y;
        col[rowptr[d.z] + r.z] = s.z;
        col[rowptr[d.w] + r.w] = s.w;
    } else {
        for (int e = base; e < E; ++e)
            col[rowptr[dst[e]] + rank[e]] = src[e];
    }
}

// layer-2 GEMM (bf16 A)
__global__ __launch_bounds__(THREADS)
void mfma_gemm2_kernel(const unsigned short* __restrict__ A, const short* __restrict__ Bfrag,
                       unsigned short* __restrict__ H, int M) {
    gemm_bf16A_body<4, 4>(A, Bfrag, H, M, (int)blockIdx.x);
}

// ================= exclusive scan, fused dis =================

#define SCAN_BLOCK 256
#define SCAN_ITEMS 4   // 1024 elements per block

__global__ __launch_bounds__(SCAN_BLOCK)
void scan_block_kernel(const int* __restrict__ in, int* __restrict__ out,
                       int* __restrict__ blockSums, float* __restrict__ dis, int n) {
    __shared__ int sdata[SCAN_BLOCK];
    int base = blockIdx.x * (SCAN_BLOCK * SCAN_ITEMS);
    int tid = threadIdx.x;
    int v[SCAN_ITEMS];
    int sum = 0;
    #pragma unroll
    for (int k = 0; k < SCAN_ITEMS; ++k) {
        int idx = base + tid * SCAN_ITEMS + k;
        v[k] = (idx < n) ? in[idx] : 0;
        if (idx < n) dis[idx] = rsqrtf((float)v[k] + 1.0f);
        sum += v[k];
    }
    sdata[tid] = sum;
    __syncthreads();
    for (int off = 1; off < SCAN_BLOCK; off <<= 1) {
        int t = (tid >= off) ? sdata[tid - off] : 0;
        __syncthreads();
        sdata[tid] += t;
        __syncthreads();
    }
    if (tid == SCAN_BLOCK - 1) blockSums[blockIdx.x] = sdata[SCAN_BLOCK - 1];
    int run = (tid == 0) ? 0 : sdata[tid - 1];
    #pragma unroll
    for (int k = 0; k < SCAN_ITEMS; ++k) {
        int idx = base + tid * SCAN_ITEMS + k;
        if (idx < n) out[idx] = run;
        run += v[k];
    }
}

__global__ __launch_bounds__(SCAN_BLOCK)
void scan_sums_kernel(int* __restrict__ blockSums, int nB) {
    __shared__ int sdata[SCAN_BLOCK];
    int tid = threadIdx.x;
    sdata[tid] = (tid < nB) ? blockSums[tid] : 0;
    __syncthreads();
    for (int off = 1; off < SCAN_BLOCK; off <<= 1) {
        int t = (tid >= off) ? sdata[tid - off] : 0;
        __syncthreads();
        sdata[tid] += t;
        __syncthreads();
    }
    int excl = (tid == 0) ? 0 : sdata[tid - 1];
    if (tid < nB) blockSums[tid] = excl;
}

__global__ __launch_bounds__(SCAN_BLOCK)
void scan_add_kernel(int* __restrict__ out, const int* __restrict__ blockSums,
                     int n, int E) {
    int base = blockIdx.x * (SCAN_BLOCK * SCAN_ITEMS);
    int add = blockSums[blockIdx.x];
    #pragma unroll
    for (int k = 0; k < SCAN_ITEMS; ++k) {
        int idx = base + threadIdx.x * SCAN_ITEMS + k;
        if (idx < n) out[idx] += add;
    }
    if (blockIdx.x == 0 && threadIdx.x == 0) out[n] = E;
}

// ================= scalarized gather, depth-8 pipeline =================
// out_i = relu(di * (di*h_i + sum_s dis[s]*h_s) + b). One wave per node;
// row base + dis[s] are wave-uniform scalars; up to 16 row loads in flight.
// OUTBF16: write output row as bf16 (layer 1 -> gemm2 input); else f32.

template<int F, int VEC, bool OUTBF16>
__global__ __launch_bounds__(THREADS)
void gather_bf16_kernel(const unsigned short* __restrict__ g, const int* __restrict__ col,
                        const int* __restrict__ rowptr, const float* __restrict__ dis,
                        const float* __restrict__ bias, void* __restrict__ outv, int N) {
    int wid = (int)((blockIdx.x * (long long)blockDim.x + threadIdx.x) >> 6);
    wid = __builtin_amdgcn_readfirstlane(wid);
    const int lane = threadIdx.x & 63;
    if (wid >= N) return;
    const float di = dis[wid];
    const int loff = lane * VEC;

    float acc0 = 0.0f, acc1 = 0.0f;

    auto loadrow = [&](int s) -> unsigned {
        const unsigned short* p = g + (size_t)s * F + loff;
        if (VEC == 2) return *(const unsigned*)p;
        else return (unsigned)*p;
    };
    auto addconv = [&](unsigned u, float w) {
        if (VEC == 2) {
            acc0 += w * bfu2f(u & 0xFFFFu);
            acc1 += w * __builtin_bit_cast(float, u & 0xFFFF0000u);
        } else {
            acc0 += w * bfu2f(u);
        }
    };

    addconv(loadrow(wid), di);   // self-loop row

    int start = __builtin_amdgcn_readfirstlane(rowptr[wid]);
    int end   = __builtin_amdgcn_readfirstlane(rowptr[wid + 1]);
    const int* c = col + start;
    int rem = end - start;

    if (rem >= 8) {
        int s0 = __builtin_amdgcn_readfirstlane(c[0]);
        int s1 = __builtin_amdgcn_readfirstlane(c[1]);
        int s2 = __builtin_amdgcn_readfirstlane(c[2]);
        int s3 = __builtin_amdgcn_readfirstlane(c[3]);
        int s4 = __builtin_amdgcn_readfirstlane(c[4]);
        int s5 = __builtin_amdgcn_readfirstlane(c[5]);
        int s6 = __builtin_amdgcn_readfirstlane(c[6]);
        int s7 = __builtin_amdgcn_readfirstlane(c[7]);
        float w0 = dis[s0], w1 = dis[s1], w2 = dis[s2], w3 = dis[s3];
        float w4 = dis[s4], w5 = dis[s5], w6 = dis[s6], w7 = dis[s7];
        unsigned u0 = loadrow(s0), u1 = loadrow(s1), u2 = loadrow(s2), u3 = loadrow(s3);
        unsigned u4 = loadrow(s4), u5 = loadrow(s5), u6 = loadrow(s6), u7 = loadrow(s7);
        c += 8; rem -= 8;
        while (rem >= 8) {
            int t0 = __builtin_amdgcn_readfirstlane(c[0]);
            int t1 = __builtin_amdgcn_readfirstlane(c[1]);
            int t2 = __builtin_amdgcn_readfirstlane(c[2]);
            int t3 = __builtin_amdgcn_readfirstlane(c[3]);
            int t4 = __builtin_amdgcn_readfirstlane(c[4]);
            int t5 = __builtin_amdgcn_readfirstlane(c[5]);
            int t6 = __builtin_amdgcn_readfirstlane(c[6]);
            int t7 = __builtin_amdgcn_readfirstlane(c[7]);
            float x0 = dis[t0], x1 = dis[t1], x2 = dis[t2], x3 = dis[t3];
            float x4 = dis[t4], x5 = dis[t5], x6 = dis[t6], x7 = dis[t7];
            unsigned v0 = loadrow(t0), v1 = loadrow(t1), v2 = loadrow(t2), v3 = loadrow(t3);
            unsigned v4 = loadrow(t4), v5 = loadrow(t5), v6 = loadrow(t6), v7 = loadrow(t7);
            addconv(u0, w0); addconv(u1, w1); addconv(u2, w2); addconv(u3, w3);
            addconv(u4, w4); addconv(u5, w5); addconv(u6, w6); addconv(u7, w7);
            u0 = v0; u1 = v1; u2 = v2; u3 = v3;
            u4 = v4; u5 = v5; u6 = v6; u7 = v7;
            w0 = x0; w1 = x1; w2 = x2; w3 = x3;
            w4 = x4; w5 = x5; w6 = x6; w7 = x7;
            c += 8; rem -= 8;
        }
        addconv(u0, w0); addconv(u1, w1); addconv(u2, w2); addconv(u3, w3);
        addconv(u4, w4); addconv(u5, w5); addconv(u6, w6); addconv(u7, w7);
    }
    if (rem >= 4) {
        int s0 = __builtin_amdgcn_readfirstlane(c[0]);
        int s1 = __builtin_amdgcn_readfirstlane(c[1]);
        int s2 = __builtin_amdgcn_readfirstlane(c[2]);
        int s3 = __builtin_amdgcn_readfirstlane(c[3]);
        float w0 = dis[s0], w1 = dis[s1], w2 = dis[s2], w3 = dis[s3];
        unsigned u0 = loadrow(s0), u1 = loadrow(s1), u2 = loadrow(s2), u3 = loadrow(s3);
        addconv(u0, w0); addconv(u1, w1); addconv(u2, w2); addconv(u3, w3);
        c += 4; rem -= 4;
    }
    while (rem > 0) {
        int s = __builtin_amdgcn_readfirstlane(c[0]);
        addconv(loadrow(s), dis[s]);
        ++c; --rem;
    }

    float v0 = fmaxf(di * acc0 + bias[loff], 0.0f);
    if (OUTBF16) {
        unsigned short* orow = (unsigned short*)outv + (size_t)wid * F + loff;
        if (VEC == 2) {
            float v1 = fmaxf(di * acc1 + bias[loff + 1], 0.0f);
            unsigned pack = f2bf_rne_u(v0) | (f2bf_rne_u(v1) << 16);
            *(unsigned*)orow = pack;
        } else {
            *orow = (unsigned short)f2bf_rne_u(v0);
        }
    } else {
        float* orow = (float*)outv + (size_t)wid * F + loff;
        if (VEC == 2) {
            float v1 = fmaxf(di * acc1 + bias[loff + 1], 0.0f);
            *(float2*)orow = make_float2(v0, v1);
        } else {
            *orow = v0;
        }
    }
}

// ================= fallback fp32 GEMM + atomic path (round-0, verified) =================

#define BM 64
#define BN 64
#define BK 16

__global__ __launch_bounds__(THREADS)
void sgemm_kernel(const float* __restrict__ A, const float* __restrict__ B,
                  float* __restrict__ C, int M, int N, int K) {
    __shared__ float As[BK][BM + 1];
    __shared__ float Bs[BK][BN + 1];

    const int tid = threadIdx.x;
    const int tr = tid / 16;
    const int tc = tid % 16;
    const int rowBase = blockIdx.y * BM;
    const int colBase = blockIdx.x * BN;

    float acc[4][4] = {};

    for (int k0 = 0; k0 < K; k0 += BK) {
        #pragma unroll
        for (int i = tid; i < BM * BK; i += THREADS) {
            int r = i / BK, c = i % BK;
            int gr = rowBase + r;
            As[c][r] = (gr < M) ? A[(size_t)gr * K + k0 + c] : 0.0f;
        }
        #pragma unroll
        for (int i = tid; i < BK * BN; i += THREADS) {
            int r = i / BN, c = i % BN;
            Bs[r][c] = B[(size_t)(k0 + r) * N + colBase + c];
        }
        __syncthreads();

        #pragma unroll
        for (int k = 0; k < BK; ++k) {
            float a[4], b[4];
            #pragma unroll
            for (int m = 0; m < 4; ++m) a[m] = As[k][tr * 4 + m];
            #pragma unroll
            for (int n = 0; n < 4; ++n) b[n] = Bs[k][tc * 4 + n];
            #pragma unroll
            for (int m = 0; m < 4; ++m)
                #pragma unroll
                for (int n = 0; n < 4; ++n)
                    acc[m][n] += a[m] * b[n];
        }
        __syncthreads();
    }

    #pragma unroll
    for (int m = 0; m < 4; ++m) {
        int gr = rowBase + tr * 4 + m;
        if (gr >= M) continue;
        #pragma unroll
        for (int n = 0; n < 4; ++n) {
            C[(size_t)gr * N + colBase + tc * 4 + n] = acc[m][n];
        }
    }
}

__global__ __launch_bounds__(THREADS)
void init_agg_kernel(const float* __restrict__ h, const float* __restrict__ dis,
                     float* __restrict__ agg, int N, int F) {
    int i = blockIdx.x * blockDim.x + threadIdx.x;
    int total = N * (F / 4);
    if (i >= total) return;
    int node = i / (F / 4);
    float d = dis[node];
    float w = d * d;
    float4 v = ((const float4*)h)[i];
    v.x *= w; v.y *= w; v.z *= w; v.w *= w;
    ((float4*)agg)[i] = v;
}

__global__ __launch_bounds__(THREADS)
void edge_scatter_kernel(const float* __restrict__ h, const int* __restrict__ src,
                         const int* __restrict__ dst, const float* __restrict__ dis,
                         float* __restrict__ agg, int E, int F) {
    int lanesPerEdge = F / 4;
    int tid = blockIdx.x * blockDim.x + threadIdx.x;
    int e = tid / lanesPerEdge;
    int c = tid % lanesPerEdge;
    if (e >= E) return;
    int s = src[e];
    int d = dst[e];
    float w = dis[s] * dis[d];
    float4 hv = ((const float4*)(h + (size_t)s * F))[c];
    float* ap = agg + (size_t)d * F + (size_t)c * 4;
    atomicAdd(ap + 0, hv.x * w);
    atomicAdd(ap + 1, hv.y * w);
    atomicAdd(ap + 2, hv.z * w);
    atomicAdd(ap + 3, hv.w * w);
}

__global__ __launch_bounds__(THREADS)
void finalize_kernel(const float* __restrict__ agg, const float* __restrict__ b,
                     float* __restrict__ out, int N, int F) {
    int i = blockIdx.x * blockDim.x + threadIdx.x;
    int total = N * (F / 4);
    if (i >= total) return;
    int c4 = i % (F / 4);
    float4 bv = ((const float4*)b)[c4];
    float4 v = ((const float4*)agg)[i];
    v.x = fmaxf(v.x + bv.x, 0.0f);
    v.y = fmaxf(v.y + bv.y, 0.0f);
    v.z = fmaxf(v.z + bv.z, 0.0f);
    v.w = fmaxf(v.w + bv.w, 0.0f);
    ((float4*)out)[i] = v;
}

__global__ __launch_bounds__(THREADS)
void fdeg_kernel(const int* __restrict__ dst, float* __restrict__ deg, int E) {
    int i = blockIdx.x * blockDim.x + threadIdx.x;
    if (i < E) atomicAdd(&deg[dst[i]], 1.0f);
}

__global__ __launch_bounds__(THREADS)
void fdis_kernel(float* __restrict__ deg, int N) {
    int i = blockIdx.x * blockDim.x + threadIdx.x;
    if (i < N) deg[i] = rsqrtf(deg[i] + 1.0f);
}

// ================= launch =================

extern "C" void kernel_launch(void* const* d_in, const int* in_sizes, int n_in,
                              void* d_out, int out_size, void* d_ws, size_t ws_size,
                              hipStream_t stream) {
    const float* x  = (const float*)d_in[0];
    const int*   ei = (const int*)d_in[1];
    const float* W1 = (const float*)d_in[2];
    const float* b1 = (const float*)d_in[3];
    const float* W2 = (const float*)d_in[4];
    const float* b2 = (const float*)d_in[5];

    const int E    = in_sizes[1] / 2;
    const int hid  = in_sizes[3];            // 128
    const int outc = in_sizes[5];            // 64
    const int inc  = in_sizes[2] / hid;      // 256
    const int N    = in_sizes[0] / inc;      // 100000

    const int* src = ei;
    const int* dst = ei + E;
    float* out = (float*)d_out;
    char* ws = (char*)d_ws;

    auto al = [](size_t v) { return (v + 255) & ~(size_t)255; };
    size_t o_dis  = 0;
    size_t o_deg  = al(o_dis + (size_t)N * 4);
    size_t o_rp   = al(o_deg + (size_t)N * 4);
    size_t o_bs   = al(o_rp + ((size_t)N + 1) * 4);
    size_t o_col  = al(o_bs + 4096);
    size_t o_rank = al(o_col + (size_t)E * 4);
    size_t o_bf1  = al(o_rank + (size_t)E * 4);
    size_t o_bf2  = al(o_bf1 + 131072);                // 8*8*1024 shorts
    size_t o_G    = al(o_bf2 + 32768);                 // 4*4*1024 shorts
    size_t o_B    = al(o_G + (size_t)N * hid * 2);     // h rows (bf16)
    size_t need   = o_B + (size_t)N * hid * 2;         // out1 (bf16)

    if (ws_size >= need && N <= SCAN_BLOCK * SCAN_BLOCK * SCAN_ITEMS &&
        hid == 128 && outc == 64 && inc == 256) {
        // ---------- CSR gather + MFMA path (round-13 structure, bf16 out1) ----------
        float* dis    = (float*)(ws + o_dis);
        int*   deg    = (int*)(ws + o_deg);
        int*   rowptr = (int*)(ws + o_rp);
        int*   bsums  = (int*)(ws + o_bs);
        int*   col    = (int*)(ws + o_col);
        int*   rank   = (int*)(ws + o_rank);
        short* bf1    = (short*)(ws + o_bf1);
        short* bf2    = (short*)(ws + o_bf2);
        unsigned short* gbuf = (unsigned short*)(ws + o_G);   // h1 bf16 (N*128), later h2 (N*64)
        unsigned short* out1 = (unsigned short*)(ws + o_B);   // layer-1 output, bf16 (N*128)

        const int nbZero  = cdiv(N, 4 * THREADS);
        const int nbHist  = cdiv(E, THREADS * HIST_ILP);
        const int nbGemm1 = cdiv(N, 128);
        const int nbFill  = cdiv(E, 4 * THREADS);

        // K0: zero deg || weight fragments
        zero_bfrag_kernel<<<nbZero + 20, THREADS, 0, stream>>>(deg, N, W1, bf1, W2, bf2, nbZero);

        // K1: hist (ILP-8) || FULL gemm1, Bresenham-interleaved
        hist_gemm1_kernel<<<nbHist + nbGemm1, THREADS, 0, stream>>>(
            dst, deg, rank, E, x, bf1, gbuf, N, nbHist, nbGemm1);

        // rowptr = exclusive_scan(deg); dis fused
        int nB = cdiv(N, SCAN_BLOCK * SCAN_ITEMS);
        scan_block_kernel<<<nB, SCAN_BLOCK, 0, stream>>>(deg, rowptr, bsums, dis, N);
        scan_sums_kernel<<<1, SCAN_BLOCK, 0, stream>>>(bsums, nB);
        scan_add_kernel<<<nB, SCAN_BLOCK, 0, stream>>>(rowptr, bsums, N, E);

        // CSR fill (atomic-free)
        fill_col_rank_kernel<<<nbFill, THREADS, 0, stream>>>(src, dst, rank, rowptr, col, E);

        // ---- layer 1 gather (depth-8, bf16 output) ----
        gather_bf16_kernel<128, 2, true><<<cdiv((long long)N * 64, THREADS), THREADS, 0, stream>>>(
            gbuf, col, rowptr, dis, b1, out1, N);

        // ---- layer 2 ----
        mfma_gemm2_kernel<<<cdiv(N, 128), THREADS, 0, stream>>>(out1, bf2, gbuf, N);
        gather_bf16_kernel<64, 1, false><<<cdiv((long long)N * 64, THREADS), THREADS, 0, stream>>>(
            gbuf, col, rowptr, dis, b2, out, N);
        return;
    }

    // ---------- fallback: round-0 atomic path ----------
    float* dis = (float*)ws;
    size_t off1 = ((size_t)N * 4 + 255) & ~(size_t)255;
    float* h1 = (float*)(ws + off1);
    size_t off2 = off1 + ((((size_t)N * hid * 4) + 255) & ~(size_t)255);
    float* agg1 = (float*)(ws + off2);
    float* h2   = agg1;
    float* agg2 = agg1 + (size_t)N * outc;

    hipMemsetAsync(dis, 0, (size_t)N * 4, stream);
    fdeg_kernel<<<cdiv(E, THREADS), THREADS, 0, stream>>>(dst, dis, E);
    fdis_kernel<<<cdiv(N, THREADS), THREADS, 0, stream>>>(dis, N);

    {
        dim3 grid(hid / BN, cdiv(N, BM));
        sgemm_kernel<<<grid, THREADS, 0, stream>>>(x, W1, h1, N, hid, inc);
    }
    init_agg_kernel<<<cdiv((long long)N * hid / 4, THREADS), THREADS, 0, stream>>>(h1, dis, agg1, N, hid);
    edge_scatter_kernel<<<cdiv((long long)E * (hid / 4), THREADS), THREADS, 0, stream>>>(
        h1, src, dst, dis, agg1, E, hid);
    finalize_kernel<<<cdiv((long long)N * hid / 4, THREADS), THREADS, 0, stream>>>(agg1, b1, h1, N, hid);

    {
        dim3 grid(outc / BN, cdiv(N, BM));
        sgemm_kernel<<<grid, THREADS, 0, stream>>>(h1, W2, h2, N, outc, hid);
    }
    init_agg_kernel<<<cdiv((long long)N * outc / 4, THREADS), THREADS, 0, stream>>>(h2, dis, agg2, N, outc);
    edge_scatter_kernel<<<cdiv((long long)E * (outc / 4), THREADS), THREADS, 0, stream>>>(
        h2, src, dst, dis, agg2, E, outc);
    finalize_kernel<<<cdiv((long long)N * outc / 4, THREADS), THREADS, 0, stream>>>(agg2, b2, out, N, outc);
}